// Round 16
// baseline (46.639 us; speedup 1.0000x reference)
//
#include <hip/hip_runtime.h>
#include <hip/hip_bf16.h>
#include <stdint.h>

// Conv2d, B=32, Cin=64, Cout=128, 3x3, stride 1, pad 1, H=W=56, fp32 in/out.
// Reference's mismatched flatten == standard conv with permuted weights:
// Weff for patch elem (c,di,dj) = K[f/192][(f%192)/64][f%64], f = c*9+di*3+dj.
// Reduction order g = di*192 + dj*64 + c => for fixed di, A's K-slice is
// CONTIGUOUS in padded-NHWC layout (dj folds into +128B position stride).
// r16: FUSED r13. Kill the xpT HBM round-trip + prep launch + gap (~10.8us
// serialized): each conv block transposes its own 10 x-rows NCHW-f32 ->
// padded-NHWC-bf16 in LDS (r4's trick, but with r13's proven barrier-free
// 18-chunk inner loop and 8-row/512-thread blocks). Co-half pairs share x
// rows and sit on the SAME XCD (consecutive work ids) for L2 reuse. Only a
// tiny 288-block weight-permute kernel remains.

#define B_   32
#define CIN  64
#define COUT 128
#define H_   56
#define HP   58          // spatially padded
#define F_   576         // 9*64 reduction length

typedef __attribute__((ext_vector_type(8))) short bf16x8;
typedef __attribute__((ext_vector_type(4))) float f32x4;

#define AS1 __attribute__((address_space(1)))
#define AS3 __attribute__((address_space(3)))

#define WG_ELEMS (COUT*F_)               // 73,728
#define WS_NEEDED ((size_t)WG_ELEMS * 2) // 147 KB
#define NWBLK (WG_ELEMS/256)             // 288 weight blocks

// conv LDS: A tile [0, 74240) = 10 padded rows x 58 pos x 128B;
// B-half [74240, 147968). Transpose scratch double-buffers in B region.
#define A_ALLOC 74240
#define LDS_TOT (A_ALLOC + 64*F_*2)      // 147,968 <= 160 KiB

// A swizzle (16B-granule involution, bits 4-6 only).
__device__ __forceinline__ int aswz(int tot) {
  return (tot & ~127) | ((tot & 127) ^ (((tot >> 7) & 7) << 4));
}

// ---------- prepass: K[kh][kw][cin][cout] f32 -> WgT[co][g] bf16 ----------
__global__ __launch_bounds__(256) void prep_w(const float* __restrict__ K,
                                              __hip_bfloat16* __restrict__ WgT) {
  int n = blockIdx.x*256 + threadIdx.x;   // 288 full blocks
  int co = n / F_, g = n % F_;
  int di = g / 192, dj = (g % 192) / 64, c = g & 63;
  int f  = c*9 + di*3 + dj;
  int kh = f / 192, kw = (f % 192) / 64, cc = f & 63;
  WgT[n] = __float2bfloat16(K[(((size_t)kh*3 + kw)*CIN + cc)*COUT + co]);
}

// ---------- fused conv: block = (b, 8 output rows, co-half), 512 thr ------
// Prologue: in-LDS transpose of 10 padded x-rows (dbuf scratch in B region,
// 11 barriers) + B-half stage (coalesced, pre-swizzled src). Then r13's
// barrier-free 18-chunk loop. Wave = output row.
__global__ __launch_bounds__(512) void conv_fused(
    const float* __restrict__ x,
    const __hip_bfloat16* __restrict__ WgT,
    float* __restrict__ out) {
  __shared__ __align__(16) char lds[LDS_TOT];
  const int t    = threadIdx.x;
  const int wave = t >> 6;               // wave w -> output row i0+w
  const int l    = t & 63;
  const int lr   = l & 15, lq = l >> 4;

  // bijective XCD swizzle: 448 = 8*56. Consecutive swz (= same XCD under
  // round-robin dispatch) are co-half pairs over the SAME x rows.
  const int bid = blockIdx.x;
  const int swz = (bid & 7) * 56 + (bid >> 3);
  const int v   = swz >> 1;              // 0..223
  const int ch  = swz & 1;               // co-half
  const int bb  = v / 7;
  const int i0  = (v % 7) * 8;

  f32x4 acc[4][4];
#pragma unroll
  for (int mi = 0; mi < 4; ++mi)
#pragma unroll
    for (int ni = 0; ni < 4; ++ni) acc[mi][ni] = (f32x4)0.f;

  const float* xb = x + (size_t)bb*CIN*H_*H_;
  const char*  wh = (const char*)WgT + (size_t)(ch*64)*1152;
  char* s0 = lds + A_ALLOC;              // scratch dbuf lives in B region
  char* s1 = s0 + 16384;

  // phaseA: load x row (i0+r-1) -> slot-swizzled f32 scratch (16 KB)
  auto phaseA = [&](int r, char* s) {
    const int h = i0 + r;
    if (h == 0 || h == HP-1) return;     // pad row: phaseB emits zeros
    const float* xr = xb + (size_t)(h-1)*H_;
    for (int idx = t; idx < CIN*14; idx += 512) {   // coalesced f32x4
      int c = idx / 14, w4 = idx % 14;
      f32x4 vv = *(const f32x4*)(xr + (size_t)c*(H_*H_) + w4*4);
      *(f32x4*)(s + c*256 + ((w4 + (c >> 3)) & 15)*16) = vv;
    }
  };
  // phaseB: scratch -> bf16 A-tile padded row r (swizzled ds_write)
  auto phaseB = [&](int r, const char* s) {
    const int h = i0 + r;
    const bool zrow = (h == 0 || h == HP-1);
    for (int idx = t; idx < HP*8; idx += 512) {     // 464 bf16x8 writes
      int wp = idx >> 3, cg = (idx & 7) * 8;
      __align__(16) __hip_bfloat16 tmp[8];
      if (zrow || wp == 0 || wp == HP-1) {
#pragma unroll
        for (int k2 = 0; k2 < 8; ++k2) tmp[k2] = __float2bfloat16(0.f);
      } else {
        int w = wp - 1, sl = w >> 2, off = w & 3;
#pragma unroll
        for (int k2 = 0; k2 < 8; ++k2) {
          int c = cg + k2;
          tmp[k2] = __float2bfloat16(
              *(const float*)(s + c*256 + ((sl + (c >> 3)) & 15)*16 + off*4));
        }
      }
      int tot = (r*HP + wp)*128 + cg*2;
      *(bf16x8*)(lds + aswz(tot)) = *(const bf16x8*)tmp;
    }
  };

  // ---- in-LDS transpose of 10 padded rows (double-buffered) ----
  phaseA(0, s0);
  __syncthreads();
#pragma unroll
  for (int r = 0; r < 10; ++r) {
    const char* sc = (r & 1) ? s1 : s0;
    phaseB(r, sc);
    if (r < 9) phaseA(r + 1, (r & 1) ? s0 : s1);
    __syncthreads();
  }

  // ---- stage B-half: 73,728B = 9 x 8KB coalesced; src pre-swizzled within
  // each 1152B co-row (read side applies the same XOR) ----
#pragma unroll
  for (int s = 0; s < 9; ++s) {
    int o  = s*8192 + t*16;
    int co = o / 1152;
    int rb = o - co*1152;
    __builtin_amdgcn_global_load_lds(
        (const AS1 void*)(wh + co*1152 + (rb ^ ((co & 7) << 4))),
        (AS3 void*)(lds + A_ALLOC + s*8192 + wave*1024), 16, 0, 0);
  }
  __syncthreads();                       // drains vmcnt; last barrier

  // ---- main loop: 18 chunks of k=32, pure LDS+MFMA, free-running waves ----
#pragma unroll
  for (int hc = 0; hc < 18; ++hc) {
    const int kg  = hc*32;
    const int di  = kg / 192;
    const int rem = kg - di*192;         // dj*64 + c0; *2 folds dj shift
    bf16x8 a[4], bq[4];
#pragma unroll
    for (int mi = 0; mi < 4; ++mi) {
      int tot = ((wave + di)*HP + mi*16 + lr)*128 + rem*2 + lq*16;
      a[mi] = *(const bf16x8*)(lds + aswz(tot));
    }
    const int kb = hc*64 + lq*16;        // byte offset within co-row
#pragma unroll
    for (int ni = 0; ni < 4; ++ni) {
      int co = ni*16 + lr;
      bq[ni] = *(const bf16x8*)(lds + A_ALLOC + co*1152 + (kb ^ ((co & 7) << 4)));
    }
    __builtin_amdgcn_s_setprio(1);
#pragma unroll
    for (int mi = 0; mi < 4; ++mi)
#pragma unroll
      for (int ni = 0; ni < 4; ++ni)
        acc[mi][ni] = __builtin_amdgcn_mfma_f32_16x16x32_bf16(
            a[mi], bq[ni], acc[mi][ni], 0, 0, 0);
    __builtin_amdgcn_s_setprio(0);
  }

  // epilogue: C/D layout col=lane&15 -> co, row=(lane>>4)*4+reg -> j
  const int i = i0 + wave;
#pragma unroll
  for (int mi = 0; mi < 4; ++mi) {
    int j0 = mi*16 + lq*4;
    if (j0 < H_) {
#pragma unroll
      for (int ni = 0; ni < 4; ++ni) {
        int co = ch*64 + ni*16 + lr;
        float* dst = out + (((size_t)(bb*COUT + co))*H_ + i)*H_ + j0;
        *(f32x4*)dst = acc[mi][ni];
      }
    }
  }
}

// ---------- fallback (workspace too small): naive fp32 direct ----------
__global__ __launch_bounds__(256) void conv_naive(const float* __restrict__ x,
                                                  const float* __restrict__ K,
                                                  float* __restrict__ out) {
  int idx = blockIdx.x*256 + threadIdx.x;
  const int total = B_*COUT*H_*H_;
  if (idx >= total) return;
  int j = idx % H_, i = (idx / H_) % H_, co = (idx / (H_*H_)) % COUT, b = idx / (H_*H_*COUT);
  float s = 0.f;
  for (int c = 0; c < CIN; ++c)
    for (int di = 0; di < 3; ++di) {
      int ii = i + di - 1;
      if (ii < 0 || ii >= H_) continue;
      for (int dj = 0; dj < 3; ++dj) {
        int jj = j + dj - 1;
        if (jj < 0 || jj >= H_) continue;
        int f = c*9 + di*3 + dj;
        int kh = f / 192, kw = (f % 192) / 64, cc = f & 63;
        s += x[(((size_t)b*CIN + c)*H_ + ii)*H_ + jj] *
             K[(((size_t)kh*3 + kw)*CIN + cc)*COUT + co];
      }
    }
  out[idx] = s;
}

extern "C" void kernel_launch(void* const* d_in, const int* in_sizes, int n_in,
                              void* d_out, int out_size, void* d_ws, size_t ws_size,
                              hipStream_t stream) {
  const float* x = (const float*)d_in[0];
  const float* K = (const float*)d_in[1];
  float* out = (float*)d_out;
  if (ws_size >= WS_NEEDED) {
    __hip_bfloat16* WgT = (__hip_bfloat16*)d_ws;
    prep_w<<<NWBLK, 256, 0, stream>>>(K, WgT);
    conv_fused<<<448, 512, 0, stream>>>(x, WgT, out);
  } else {
    conv_naive<<<(B_*COUT*H_*H_ + 255)/256, 256, 0, stream>>>(x, K, out);
  }
}

// Round 18
// 38.851 us; speedup vs baseline: 1.2005x; 1.2005x over previous
//
#include <hip/hip_runtime.h>
#include <hip/hip_bf16.h>
#include <stdint.h>

// Conv2d, B=32, Cin=64, Cout=128, 3x3, stride 1, pad 1, H=W=56, fp32 in/out.
// Reference's mismatched flatten == standard conv with permuted weights:
// Weff for patch elem (c,di,dj) = K[f/192][(f%192)/64][f%64], f = c*9+di*3+dj.
// Reduction order g = di*192 + dj*64 + c => for fixed di, A's K-slice is
// CONTIGUOUS in padded-NHWC layout (dj folds into +128B position stride).
// r18: r17 with the trample fix. r17's A-staging wrote 45,056B into a
// 44,544B region, overwriting the first 512B of B (absmax 54.7). Tail stage
// is now lane-predicated (r14/r15-proven pattern). LDS 81,408B -> 2 blocks/CU
// co-resident: one block's stage/store overlaps the other's compute.

#define B_   32
#define CIN  64
#define COUT 128
#define H_   56
#define HP   58          // spatially padded
#define F_   576         // 9*64 reduction length

typedef __attribute__((ext_vector_type(8))) short bf16x8;
typedef __attribute__((ext_vector_type(4))) float f32x4;

#define AS1 __attribute__((address_space(1)))
#define AS3 __attribute__((address_space(3)))

#define XP_ELEMS (B_*HP*HP*CIN)          // 6,889,472
#define XP_SLACK 4096
#define XP_TOTAL (XP_ELEMS + XP_SLACK)
#define WG_ELEMS (COUT*F_)               // 73,728
#define WS_NEEDED ((size_t)(XP_TOTAL + WG_ELEMS) * 2)

#define NROW   (B_*HP)                   // 1856 x-row blocks
#define NWBLK  (WG_ELEMS/256)            // 288 weight blocks

// conv LDS: A tile [0, 44544) = 6 padded rows x 58 pos x 128B;
// B-quarter [44544, 81408). A-stage tail is PREDICATED to stay < A_BYTES.
#define A_BYTES 44544
#define B_OFF   A_BYTES
#define LDS_TOT (A_BYTES + 32*F_*2)      // 81,408 -> 2 blocks/CU (162,816)

// A swizzle (16B-granule involution, bits 4-6 only).
__device__ __forceinline__ int aswz(int tot) {
  return (tot & ~127) | ((tot & 127) ^ (((tot >> 7) & 7) << 4));
}

// ---------- fused prepass: x NCHW f32 -> padded NHWC bf16; K -> WgT[co][g] ----
__global__ __launch_bounds__(256) void prep_all(const float* __restrict__ x,
                                                const float* __restrict__ K,
                                                __hip_bfloat16* __restrict__ xpT,
                                                __hip_bfloat16* __restrict__ WgT) {
  const int id = blockIdx.x;
  const int t  = threadIdx.x;

  if (id > NROW) {                       // ---- weight permute blocks ----
    int n = (id - (NROW + 1))*256 + t;   // 288 full blocks
    int co = n / F_, g = n % F_;
    int di = g / 192, dj = (g % 192) / 64, c = g & 63;
    int f  = c*9 + di*3 + dj;
    int kh = f / 192, kw = (f % 192) / 64, cc = f & 63;
    WgT[n] = __float2bfloat16(K[(((size_t)kh*3 + kw)*CIN + cc)*COUT + co]);
    return;
  }
  if (id == NROW) {                      // ---- slack zero-fill ----
    bf16x8 z = (bf16x8)0;
    for (int idx = t; idx < XP_SLACK/8; idx += 256)
      ((bf16x8*)(xpT + XP_ELEMS))[idx] = z;
    return;
  }

  const int b = id / HP, h = id % HP;
  __hip_bfloat16* orow = xpT + (size_t)(b*HP + h) * HP * CIN;
  if (h == 0 || h == HP-1) {             // top/bottom pad rows
    bf16x8 z = (bf16x8)0;
    for (int idx = t; idx < HP*CIN/8; idx += 256) ((bf16x8*)orow)[idx] = z;
    return;
  }
  // slot-swizzled scratch: scr[c][slot][4], slot = (w4 + (c>>3)) & 15.
  __shared__ __align__(16) float scr[CIN*64];      // 16 KB
  const float* xrow = x + ((size_t)(b*CIN)*H_ + (h-1)) * H_;
  for (int idx = t; idx < CIN*14; idx += 256) {    // coalesced f32x4 reads
    int c = idx / 14, w4 = idx % 14;
    f32x4 v = *(const f32x4*)(xrow + (size_t)c*(H_*H_) + w4*4);
    *(f32x4*)&scr[c*64 + ((w4 + (c >> 3)) & 15)*4] = v;
  }
  __syncthreads();
  for (int idx = t; idx < HP*8; idx += 256) {      // bf16x8 writes
    int wp = idx >> 3, cg = (idx & 7) * 8;
    __align__(16) __hip_bfloat16 tmp[8];
    if (wp == 0 || wp == HP-1) {
#pragma unroll
      for (int k2 = 0; k2 < 8; ++k2) tmp[k2] = __float2bfloat16(0.f);
    } else {
      int w = wp - 1, sl = w >> 2, off = w & 3;
#pragma unroll
      for (int k2 = 0; k2 < 8; ++k2) {
        int c = cg + k2;
        tmp[k2] = __float2bfloat16(scr[c*64 + ((sl + (c >> 3)) & 15)*4 + off]);
      }
    }
    *(bf16x8*)(orow + (size_t)wp*CIN + cg) = *(const bf16x8*)tmp;
  }
}

// ---------- main: implicit GEMM, block = (b, 4 rows, co-quarter) ----------
// 256 thr / 4 waves; wave = output row; per wave 64j x 32co, acc 4x2.
// Stage A+B once, ONE barrier, 18 unrolled chunks of pure ds_read+MFMA.
__global__ __launch_bounds__(256) void conv_mfma(
    const __hip_bfloat16* __restrict__ xpT,
    const __hip_bfloat16* __restrict__ WgT,
    float* __restrict__ out) {
  __shared__ __align__(16) char lds[LDS_TOT];
  const int t    = threadIdx.x;
  const int wave = t >> 6;               // wave w -> output row i0+w
  const int l    = t & 63;
  const int lr   = l & 15, lq = l >> 4;

  // bijective XCD swizzle: 1792 = 8*224; consecutive swz = same XCD.
  // swz -> (v, q4): 4 co-quarters of one (bb,itile) are consecutive.
  const int bid = blockIdx.x;
  const int swz = (bid & 7) * 224 + (bid >> 3);
  const int q4  = swz & 3;               // co-quarter
  const int v   = swz >> 2;              // 0..447
  const int bb  = v / 14;
  const int i0  = (v % 14) * 4;

  f32x4 acc[4][2];
#pragma unroll
  for (int mi = 0; mi < 4; ++mi)
#pragma unroll
    for (int ni = 0; ni < 2; ++ni) acc[mi][ni] = (f32x4)0.f;

  const char* xb = (const char*)xpT + (size_t)(bb*HP + i0) * HP * CIN * 2;
  const char* wh = (const char*)WgT + (size_t)(q4*32)*1152;

  // ---- stage A once: 44,544B; tail stage lane-predicated (no trample) ----
#pragma unroll
  for (int s = 0; s < 11; ++s) {
    int o = s*4096 + t*16;
    if (o < A_BYTES)                     // s<10: always true; s=10: t<224
      __builtin_amdgcn_global_load_lds(
          (const AS1 void*)(xb + aswz(o)),
          (AS3 void*)(lds + s*4096 + wave*1024), 16, 0, 0);
  }
  // ---- stage B-quarter once: 36,864B = 9 x 4KB coalesced; src pre-swizzled
  // within each 1152B co-row (read side applies same XOR) ----
#pragma unroll
  for (int s = 0; s < 9; ++s) {
    int o  = s*4096 + t*16;
    int co = o / 1152;                   // 0..31
    int rb = o - co*1152;
    __builtin_amdgcn_global_load_lds(
        (const AS1 void*)(wh + co*1152 + (rb ^ ((co & 7) << 4))),
        (AS3 void*)(lds + B_OFF + s*4096 + wave*1024), 16, 0, 0);
  }
  __syncthreads();                       // the ONLY barrier

  // ---- main loop: 18 chunks of k=32, pure LDS+MFMA, free-running waves ----
#pragma unroll
  for (int hc = 0; hc < 18; ++hc) {
    const int kg  = hc*32;
    const int di  = kg / 192;
    const int rem = kg - di*192;         // dj*64 + c0; *2 folds dj shift
    bf16x8 a[4], bq[2];
#pragma unroll
    for (int mi = 0; mi < 4; ++mi) {
      int tot = ((wave + di)*HP + mi*16 + lr)*128 + rem*2 + lq*16;
      a[mi] = *(const bf16x8*)(lds + aswz(tot));
    }
    const int kb = hc*64 + lq*16;        // byte offset within co-row
#pragma unroll
    for (int ni = 0; ni < 2; ++ni) {
      int co = ni*16 + lr;
      bq[ni] = *(const bf16x8*)(lds + B_OFF + co*1152 + (kb ^ ((co & 7) << 4)));
    }
    __builtin_amdgcn_s_setprio(1);
#pragma unroll
    for (int mi = 0; mi < 4; ++mi)
#pragma unroll
      for (int ni = 0; ni < 2; ++ni)
        acc[mi][ni] = __builtin_amdgcn_mfma_f32_16x16x32_bf16(
            a[mi], bq[ni], acc[mi][ni], 0, 0, 0);
    __builtin_amdgcn_s_setprio(0);
  }

  // epilogue: C/D layout col=lane&15 -> co, row=(lane>>4)*4+reg -> j
  const int i = i0 + wave;
#pragma unroll
  for (int mi = 0; mi < 4; ++mi) {
    int j0 = mi*16 + lq*4;
    if (j0 < H_) {
#pragma unroll
      for (int ni = 0; ni < 2; ++ni) {
        int co = q4*32 + ni*16 + lr;
        float* dst = out + (((size_t)(bb*COUT + co))*H_ + i)*H_ + j0;
        *(f32x4*)dst = acc[mi][ni];
      }
    }
  }
}

// ---------- fallback (workspace too small): naive fp32 direct ----------
__global__ __launch_bounds__(256) void conv_naive(const float* __restrict__ x,
                                                  const float* __restrict__ K,
                                                  float* __restrict__ out) {
  int idx = blockIdx.x*256 + threadIdx.x;
  const int total = B_*COUT*H_*H_;
  if (idx >= total) return;
  int j = idx % H_, i = (idx / H_) % H_, co = (idx / (H_*H_)) % COUT, b = idx / (H_*H_*COUT);
  float s = 0.f;
  for (int c = 0; c < CIN; ++c)
    for (int di = 0; di < 3; ++di) {
      int ii = i + di - 1;
      if (ii < 0 || ii >= H_) continue;
      for (int dj = 0; dj < 3; ++dj) {
        int jj = j + dj - 1;
        if (jj < 0 || jj >= H_) continue;
        int f = c*9 + di*3 + dj;
        int kh = f / 192, kw = (f % 192) / 64, cc = f & 63;
        s += x[(((size_t)b*CIN + c)*H_ + ii)*H_ + jj] *
             K[(((size_t)kh*3 + kw)*CIN + cc)*COUT + co];
      }
    }
  out[idx] = s;
}

extern "C" void kernel_launch(void* const* d_in, const int* in_sizes, int n_in,
                              void* d_out, int out_size, void* d_ws, size_t ws_size,
                              hipStream_t stream) {
  const float* x = (const float*)d_in[0];
  const float* K = (const float*)d_in[1];
  float* out = (float*)d_out;
  if (ws_size >= WS_NEEDED) {
    __hip_bfloat16* xpT = (__hip_bfloat16*)d_ws;
    __hip_bfloat16* WgT = xpT + XP_TOTAL;
    prep_all<<<NROW + 1 + NWBLK, 256, 0, stream>>>(x, K, xpT, WgT);
    conv_mfma<<<1792, 256, 0, stream>>>(xpT, WgT, out);
  } else {
    conv_naive<<<(B_*COUT*H_*H_ + 255)/256, 256, 0, stream>>>(x, K, out);
  }
}